// Round 1
// baseline (200.253 us; speedup 1.0000x reference)
//
#include <hip/hip_runtime.h>

#define LN2F 0.69314718055994530942f
#define RS5F 0.4472135954999579f  // 1/sqrt(5)

// One block per batch item b; thread k = symbol-combination index (K=256).
// idx bits: c0=(k>>6)&3 (slowest, tx 0) ... c3=k&3 (tx 3), matching
// meshgrid(indexing='ij').reshape(-1).
__global__ __launch_bounds__(256) void mfnet_layer_kernel(
    const float* __restrict__ log_qi,   // (N,4,4)
    const float* __restrict__ G,        // (N,8,4)
    const float* __restrict__ sqrt_2rho,// (N,)
    const float* __restrict__ alpha_ptr,// (1,)
    float* __restrict__ out)            // (N,4,4)
{
    const int b    = blockIdx.x;
    const int k    = threadIdx.x;
    const int lane = k & 63;
    const int wave = k >> 6;

    __shared__ float sG[32];
    __shared__ float slq[16];
    __shared__ float sc[4 * 65];   // stride 65: avoid 4-way bank conflict at xi=3
    __shared__ float sex[4];

    if (k < 32) sG[k]  = G[(size_t)b * 32 + k];
    if (k < 16) slq[k] = log_qi[(size_t)b * 16 + k];
    const float rho   = sqrt_2rho[b];
    const float alpha = alpha_ptr[0];
    __syncthreads();

    const int c0 = (k >> 6) & 3;
    const int c1 = (k >> 4) & 3;
    const int c2 = (k >> 2) & 3;
    const int c3 = k & 3;
    const float s0 = (float)(2 * c0 - 3) * RS5F;
    const float s1 = (float)(2 * c1 - 3) * RS5F;
    const float s2 = (float)(2 * c2 - 3) * RS5F;
    const float s3 = (float)(2 * c3 - 3) * RS5F;

    // log_p[k] = sum_r laplace_log_cdf(rho * (G[r,:] . s))
    float log_p = 0.0f;
#pragma unroll
    for (int r = 0; r < 8; ++r) {
        float t = sG[r * 4 + 0] * s0 + sG[r * 4 + 1] * s1 +
                  sG[r * 4 + 2] * s2 + sG[r * 4 + 3] * s3;
        float x = rho * t;
        float e = __expf(-fabsf(x));          // exp(-|x|), safe both branches
        float l = __logf(1.0f - 0.5f * e);    // arg in [0.5, 1) -> fine
        log_p += (x < 0.0f) ? (x - LN2F) : l;
    }

    const int ci[4] = {c0, c1, c2, c3};

#pragma unroll
    for (int xi = 0; xi < 4; ++xi) {
        // w = prod_{t != xi} qi[t, ci[t]] with qi = softmax(slq[t,:])
        float w = 1.0f;
#pragma unroll
        for (int t = 0; t < 4; ++t) {
            if (t == xi) continue;
            float e0 = __expf(slq[t * 4 + 0]);
            float e1 = __expf(slq[t * 4 + 1]);
            float e2 = __expf(slq[t * 4 + 2]);
            float e3 = __expf(slq[t * 4 + 3]);
            float den = e0 + e1 + e2 + e3;
            int c = ci[t];
            float num = (c == 0) ? e0 : (c == 1) ? e1 : (c == 2) ? e2 : e3;
            w *= num / den;
        }
        float cval = w * log_p;

        // regroup so combos sharing s=(k>>sh)&3 are contiguous (64 each)
        const int sh   = 6 - 2 * xi;
        const int s    = (k >> sh) & 3;
        const int rest = ((k >> (sh + 2)) << sh) | (k & ((1 << sh) - 1));
        sc[s * 65 + rest] = cval;
        __syncthreads();

        // wave `wave` reduces group `wave` (64 contiguous values)
        float v = sc[wave * 65 + lane];
#pragma unroll
        for (int off = 32; off >= 1; off >>= 1)
            v += __shfl_xor(v, off, 64);
        if (lane == 0) sex[wave] = v;
        __syncthreads();

        // sequential state update: row xi blend, then row-max renorm of ALL rows
        if (k == 0) {
#pragma unroll
            for (int ss = 0; ss < 4; ++ss)
                slq[xi * 4 + ss] = (1.0f - alpha) * slq[xi * 4 + ss] + alpha * sex[ss];
#pragma unroll
            for (int t = 0; t < 4; ++t) {
                float m = fmaxf(fmaxf(slq[t * 4 + 0], slq[t * 4 + 1]),
                                fmaxf(slq[t * 4 + 2], slq[t * 4 + 3]));
                slq[t * 4 + 0] -= m;
                slq[t * 4 + 1] -= m;
                slq[t * 4 + 2] -= m;
                slq[t * 4 + 3] -= m;
            }
        }
        __syncthreads();
    }

    if (k < 16) out[(size_t)b * 16 + k] = slq[k];
}

extern "C" void kernel_launch(void* const* d_in, const int* in_sizes, int n_in,
                              void* d_out, int out_size, void* d_ws, size_t ws_size,
                              hipStream_t stream) {
    const float* log_qi = (const float*)d_in[0];
    const float* G      = (const float*)d_in[1];
    const float* rho    = (const float*)d_in[2];
    // d_in[3] = n_var — unused by the reference
    const float* alpha  = (const float*)d_in[4];
    float* out = (float*)d_out;

    const int N = in_sizes[2];  // 32768 batch items (size of sqrt_2rho)
    mfnet_layer_kernel<<<N, 256, 0, stream>>>(log_qi, G, rho, alpha, out);
}

// Round 2
// 143.732 us; speedup vs baseline: 1.3932x; 1.3932x over previous
//
#include <hip/hip_runtime.h>

#define LN2F 0.69314718055994530942f
#define RS5F 0.4472135954999579f  // 1/sqrt(5)

// One block per batch item b; thread k = symbol-combination index (K=256).
// c0=(k>>6)&3 (tx0, slowest) ... c3=k&3 (tx3), matching meshgrid 'ij'.
__global__ __launch_bounds__(256) void mfnet_layer_kernel(
    const float* __restrict__ log_qi,   // (N,4,4)
    const float* __restrict__ G,        // (N,8,4)
    const float* __restrict__ sqrt_2rho,// (N,)
    const float* __restrict__ alpha_ptr,// (1,)
    float* __restrict__ out)            // (N,4,4)
{
    const int b    = blockIdx.x;
    const int k    = threadIdx.x;
    const int lane = k & 63;
    const int wave = k >> 6;

    __shared__ float sG[32];
    __shared__ float slq[16];
    __shared__ float qn[16];    // softmax(slq) rows, maintained incrementally
    __shared__ float part[16];  // per-wave partial sums [wave*4 + s] (or [s] for xi=0)

    if (k < 32) sG[k]  = G[(size_t)b * 32 + k];
    if (k < 16) slq[k] = log_qi[(size_t)b * 16 + k];
    // threads 0-3: initial softmax row t=k directly from global (tiny, avoids a barrier)
    if (k < 4) {
        const float* row = log_qi + (size_t)b * 16 + k * 4;
        float e0 = __expf(row[0]), e1 = __expf(row[1]);
        float e2 = __expf(row[2]), e3 = __expf(row[3]);
        float inv = 1.0f / (e0 + e1 + e2 + e3);
        qn[k * 4 + 0] = e0 * inv; qn[k * 4 + 1] = e1 * inv;
        qn[k * 4 + 2] = e2 * inv; qn[k * 4 + 3] = e3 * inv;
    }
    const float rho   = sqrt_2rho[b];
    const float alpha = alpha_ptr[0];
    __syncthreads();

    const int c0 = (k >> 6) & 3;
    const int c1 = (k >> 4) & 3;
    const int c2 = (k >> 2) & 3;
    const int c3 = k & 3;
    // fold rho into symbol values
    const float s0 = rho * (float)(2 * c0 - 3) * RS5F;
    const float s1 = rho * (float)(2 * c1 - 3) * RS5F;
    const float s2 = rho * (float)(2 * c2 - 3) * RS5F;
    const float s3 = rho * (float)(2 * c3 - 3) * RS5F;

    // log_p[k] = sum_r laplace_log_cdf(rho * (G[r,:] . s))
    float log_p = 0.0f;
#pragma unroll
    for (int r = 0; r < 8; ++r) {
        float x = sG[r * 4 + 0] * s0 + sG[r * 4 + 1] * s1 +
                  sG[r * 4 + 2] * s2 + sG[r * 4 + 3] * s3;
        float e = __expf(-fabsf(x));
        float l = __logf(1.0f - 0.5f * e);
        log_p += (x < 0.0f) ? (x - LN2F) : l;
    }

    const int ci[4] = {c0, c1, c2, c3};

#pragma unroll
    for (int xi = 0; xi < 4; ++xi) {
        // w*log_p, w = prod_{t != xi} qn[t][ci[t]] (broadcast LDS reads)
        float v = log_p;
#pragma unroll
        for (int t = 0; t < 4; ++t)
            if (t != xi) v *= qn[t * 4 + ci[t]];

        // segmented sum over the 4 non-group lane-bit positions
        if (xi == 0) {            // s = wave; full-wave reduce
            v += __shfl_xor(v, 1, 64);  v += __shfl_xor(v, 2, 64);
            v += __shfl_xor(v, 4, 64);  v += __shfl_xor(v, 8, 64);
            v += __shfl_xor(v, 16, 64); v += __shfl_xor(v, 32, 64);
            if (lane == 0) part[wave] = v;                     // index == s
        } else if (xi == 1) {     // s = lane bits 4-5; sum bits 0-3
            v += __shfl_xor(v, 1, 64);  v += __shfl_xor(v, 2, 64);
            v += __shfl_xor(v, 4, 64);  v += __shfl_xor(v, 8, 64);
            if ((lane & 15) == 0) part[wave * 4 + (lane >> 4)] = v;
        } else if (xi == 2) {     // s = lane bits 2-3; sum bits 0,1,4,5
            v += __shfl_xor(v, 1, 64);  v += __shfl_xor(v, 2, 64);
            v += __shfl_xor(v, 16, 64); v += __shfl_xor(v, 32, 64);
            if (lane < 16 && (lane & 3) == 0) part[wave * 4 + (lane >> 2)] = v;
        } else {                  // s = lane bits 0-1; sum bits 2-5
            v += __shfl_xor(v, 4, 64);  v += __shfl_xor(v, 8, 64);
            v += __shfl_xor(v, 16, 64); v += __shfl_xor(v, 32, 64);
            if (lane < 4) part[wave * 4 + lane] = v;
        }
        __syncthreads();

        // serial state update (thread 0): combine partials, blend, renorm, refresh qn row
        if (k == 0) {
            float ex[4];
#pragma unroll
            for (int s = 0; s < 4; ++s)
                ex[s] = (xi == 0) ? part[s]
                                  : part[s] + part[4 + s] + part[8 + s] + part[12 + s];
#pragma unroll
            for (int s = 0; s < 4; ++s)
                slq[xi * 4 + s] = (1.0f - alpha) * slq[xi * 4 + s] + alpha * ex[s];
#pragma unroll
            for (int t = 0; t < 4; ++t) {
                float m = fmaxf(fmaxf(slq[t * 4 + 0], slq[t * 4 + 1]),
                                fmaxf(slq[t * 4 + 2], slq[t * 4 + 3]));
                slq[t * 4 + 0] -= m; slq[t * 4 + 1] -= m;
                slq[t * 4 + 2] -= m; slq[t * 4 + 3] -= m;
            }
            if (xi < 3) {   // refresh softmax row xi (renorm never changes qn)
                float e0 = __expf(slq[xi * 4 + 0]), e1 = __expf(slq[xi * 4 + 1]);
                float e2 = __expf(slq[xi * 4 + 2]), e3 = __expf(slq[xi * 4 + 3]);
                float inv = 1.0f / (e0 + e1 + e2 + e3);
                qn[xi * 4 + 0] = e0 * inv; qn[xi * 4 + 1] = e1 * inv;
                qn[xi * 4 + 2] = e2 * inv; qn[xi * 4 + 3] = e3 * inv;
            }
        }
        __syncthreads();
    }

    if (k < 16) out[(size_t)b * 16 + k] = slq[k];
}

extern "C" void kernel_launch(void* const* d_in, const int* in_sizes, int n_in,
                              void* d_out, int out_size, void* d_ws, size_t ws_size,
                              hipStream_t stream) {
    const float* log_qi = (const float*)d_in[0];
    const float* G      = (const float*)d_in[1];
    const float* rho    = (const float*)d_in[2];
    // d_in[3] = n_var — unused by the reference
    const float* alpha  = (const float*)d_in[4];
    float* out = (float*)d_out;

    const int N = in_sizes[2];  // 32768 batch items
    mfnet_layer_kernel<<<N, 256, 0, stream>>>(log_qi, G, rho, alpha, out);
}

// Round 3
// 105.138 us; speedup vs baseline: 1.9047x; 1.3671x over previous
//
#include <hip/hip_runtime.h>

#define LN2F 0.69314718055994530942f
#define RS5F 0.4472135954999579f  // 1/sqrt(5)

// 2-bit select from 4 register values (compiler -> cndmask tree)
#define SEL4(q, c) ( ((c)&2) ? ( ((c)&1) ? (q)[3] : (q)[2] ) : ( ((c)&1) ? (q)[1] : (q)[0] ) )

// One WAVE per batch item (4 items / 256-thread block). No LDS, no barriers.
// Lane l holds 4 combos: A=2l, B=2l+1, C=255-A, D=255-B (C,D are digit
// complements of A,B -> share |x| in the laplace evals).
// Digits of A (c0 slowest, per meshgrid 'ij'): c0=l5, c1=(l>>3)&3,
// c2=(l>>1)&3, c3=2*(l&1). B: same but c3=2*(l&1)+1. C/D: 3-c each.
__global__ __launch_bounds__(256) void mfnet_layer_kernel(
    const float* __restrict__ log_qi,   // (N,4,4)
    const float* __restrict__ G,        // (N,8,4)
    const float* __restrict__ sqrt_2rho,// (N,)
    const float* __restrict__ alpha_ptr,// (1,)
    float* __restrict__ out,            // (N,4,4)
    int N)
{
    const int lane = threadIdx.x & 63;
    // force wave-uniform item index -> SGPR -> s_load for G/log_qi/rho
    const int item = __builtin_amdgcn_readfirstlane(
        (int)(blockIdx.x * 4 + (threadIdx.x >> 6)));
    if (item >= N) return;

    float g[32];
#pragma unroll
    for (int i = 0; i < 32; ++i) g[i] = G[(size_t)item * 32 + i];
    float slq[16];
#pragma unroll
    for (int i = 0; i < 16; ++i) slq[i] = log_qi[(size_t)item * 16 + i];
    const float rho   = sqrt_2rho[item];
    const float alpha = alpha_ptr[0];
    const float alm1  = 1.0f - alpha;

    const int l0  = lane & 1;
    const int l12 = (lane >> 1) & 3;
    const int l34 = (lane >> 3) & 3;
    const int l5  = (lane >> 5) & 1;

    // symbols (rho folded) for combo A
    const float s0 = rho * (float)(2 * l5  - 3) * RS5F;
    const float s1 = rho * (float)(2 * l34 - 3) * RS5F;
    const float s2 = rho * (float)(2 * l12 - 3) * RS5F;
    const float s3 = rho * (float)(4 * l0  - 3) * RS5F;
    const float dlt = rho * 2.0f * RS5F;   // sym(c3B) - sym(c3A)

    // ---- log_p for the 4 combos (paired: C=-A, D=-B share exp/log) ----
    float lpA = 0.0f, lpB = 0.0f, lpC = 0.0f, lpD = 0.0f;
#pragma unroll
    for (int r = 0; r < 8; ++r) {
        float xA = g[r*4+0]*s0 + g[r*4+1]*s1 + g[r*4+2]*s2 + g[r*4+3]*s3;
        float xB = xA + g[r*4+3]*dlt;
        {
            float ax = fabsf(xA);
            float e  = __expf(-ax);
            float lg = __logf(1.0f - 0.5f * e);
            float ng = -ax - LN2F;
            lpA += (xA < 0.0f) ? ng : lg;
            lpC += (xA < 0.0f) ? lg : ng;
        }
        {
            float ax = fabsf(xB);
            float e  = __expf(-ax);
            float lg = __logf(1.0f - 0.5f * e);
            float ng = -ax - LN2F;
            lpB += (xB < 0.0f) ? ng : lg;
            lpD += (xB < 0.0f) ? lg : ng;
        }
    }

    // ---- softmax rows, replicated in every lane ----
    float qn[16];
#pragma unroll
    for (int t = 0; t < 4; ++t) {
        float e0 = __expf(slq[t*4+0]), e1 = __expf(slq[t*4+1]);
        float e2 = __expf(slq[t*4+2]), e3 = __expf(slq[t*4+3]);
        float inv = 1.0f / (e0 + e1 + e2 + e3);
        qn[t*4+0] = e0*inv; qn[t*4+1] = e1*inv;
        qn[t*4+2] = e2*inv; qn[t*4+3] = e3*inv;
    }

    // cached per-row lookups (A-side digit, C-side = complement)
    float q0A = l5 ? qn[1] : qn[0];
    float q0C = l5 ? qn[2] : qn[3];
    float q1A = SEL4(qn + 4,  l34);
    float q1C = SEL4(qn + 4,  l34 ^ 3);
    float q2A = SEL4(qn + 8,  l12);
    float q2C = SEL4(qn + 8,  l12 ^ 3);
    float q3A = l0 ? qn[12+2] : qn[12+0];   // c3A = 2*l0
    float q3B = l0 ? qn[12+3] : qn[12+1];   // c3B = 2*l0+1
    float q3C = l0 ? qn[12+1] : qn[12+3];   // 3-c3A
    float q3D = l0 ? qn[12+0] : qn[12+2];   // 3-c3B

#pragma unroll
    for (int xi = 0; xi < 4; ++xi) {
        float PA, PC;
        if      (xi == 0) { PA = q1A*q2A;     PC = q1C*q2C;     }
        else if (xi == 1) { PA = q0A*q2A;     PC = q0C*q2C;     }
        else if (xi == 2) { PA = q0A*q1A;     PC = q0C*q1C;     }
        else              { PA = q0A*q1A*q2A; PC = q0C*q1C*q2C; }

        float vA, vB, vC, vD;
        if (xi < 3) {
            vA = lpA*PA*q3A; vB = lpB*PA*q3B;
            vC = lpC*PC*q3C; vD = lpD*PC*q3D;
        } else {
            vA = lpA*PA; vB = lpB*PA; vC = lpC*PC; vD = lpD*PC;
        }

        float ex0, ex1, ex2, ex3;
        if (xi == 0) {
            // group = c0: A,B -> l5; C,D -> 3-l5. Reduce over bits 0-4.
            float SAB = vA + vB, SCD = vC + vD;
#pragma unroll
            for (int off = 1; off <= 16; off <<= 1) {
                SAB += __shfl_xor(SAB, off, 64);
                SCD += __shfl_xor(SCD, off, 64);
            }
            ex0 = __shfl(SAB, 0, 64);  ex1 = __shfl(SAB, 32, 64);
            ex3 = __shfl(SCD, 0, 64);  ex2 = __shfl(SCD, 32, 64);
        } else if (xi == 1) {
            // group = c1 = bits 3-4; reduce over bits {0,1,2,5}
            float SAB = vA + vB, SCD = vC + vD;
            SAB += __shfl_xor(SAB, 1, 64);  SCD += __shfl_xor(SCD, 1, 64);
            SAB += __shfl_xor(SAB, 2, 64);  SCD += __shfl_xor(SCD, 2, 64);
            SAB += __shfl_xor(SAB, 4, 64);  SCD += __shfl_xor(SCD, 4, 64);
            SAB += __shfl_xor(SAB, 32, 64); SCD += __shfl_xor(SCD, 32, 64);
            float T = SAB + __shfl_xor(SCD, 24, 64);  // flip bits 3-4
            ex0 = __shfl(T, 0, 64);  ex1 = __shfl(T, 8, 64);
            ex2 = __shfl(T, 16, 64); ex3 = __shfl(T, 24, 64);
        } else if (xi == 2) {
            // group = c2 = bits 1-2; reduce over bits {0,3,4,5}
            float SAB = vA + vB, SCD = vC + vD;
            SAB += __shfl_xor(SAB, 1, 64);  SCD += __shfl_xor(SCD, 1, 64);
            SAB += __shfl_xor(SAB, 8, 64);  SCD += __shfl_xor(SCD, 8, 64);
            SAB += __shfl_xor(SAB, 16, 64); SCD += __shfl_xor(SCD, 16, 64);
            SAB += __shfl_xor(SAB, 32, 64); SCD += __shfl_xor(SCD, 32, 64);
            float T = SAB + __shfl_xor(SCD, 6, 64);   // flip bits 1-2
            ex0 = __shfl(T, 0, 64); ex1 = __shfl(T, 2, 64);
            ex2 = __shfl(T, 4, 64); ex3 = __shfl(T, 6, 64);
        } else {
            // group = c3: A->2*l0, D->2-2*l0 (even groups); B,C odd groups
            float P = vA + __shfl_xor(vD, 1, 64);  // groups {0,2} by l0
            float Q = vB + __shfl_xor(vC, 1, 64);  // groups {1,3} by l0
#pragma unroll
            for (int off = 2; off <= 32; off <<= 1) {
                P += __shfl_xor(P, off, 64);
                Q += __shfl_xor(Q, off, 64);
            }
            ex0 = __shfl(P, 0, 64); ex2 = __shfl(P, 1, 64);
            ex1 = __shfl(Q, 0, 64); ex3 = __shfl(Q, 1, 64);
        }

        // blend row xi (replicated in all lanes)
        slq[xi*4+0] = alm1*slq[xi*4+0] + alpha*ex0;
        slq[xi*4+1] = alm1*slq[xi*4+1] + alpha*ex1;
        slq[xi*4+2] = alm1*slq[xi*4+2] + alpha*ex2;
        slq[xi*4+3] = alm1*slq[xi*4+3] + alpha*ex3;

        // renorm: all rows at round 0; afterwards only row xi (others have max 0)
        const int tlo = (xi == 0) ? 0 : xi;
        const int thi = (xi == 0) ? 3 : xi;
#pragma unroll
        for (int t = tlo; t <= thi; ++t) {
            float m = fmaxf(fmaxf(slq[t*4+0], slq[t*4+1]),
                            fmaxf(slq[t*4+2], slq[t*4+3]));
            slq[t*4+0] -= m; slq[t*4+1] -= m;
            slq[t*4+2] -= m; slq[t*4+3] -= m;
        }

        // refresh softmax row xi + its cached lookups (needed by later rounds)
        if (xi < 3) {
            float e0 = __expf(slq[xi*4+0]), e1 = __expf(slq[xi*4+1]);
            float e2 = __expf(slq[xi*4+2]), e3 = __expf(slq[xi*4+3]);
            float inv = 1.0f / (e0 + e1 + e2 + e3);
            qn[xi*4+0] = e0*inv; qn[xi*4+1] = e1*inv;
            qn[xi*4+2] = e2*inv; qn[xi*4+3] = e3*inv;
            if (xi == 0) {
                q0A = l5 ? qn[1] : qn[0];
                q0C = l5 ? qn[2] : qn[3];
            } else if (xi == 1) {
                q1A = SEL4(qn + 4, l34);
                q1C = SEL4(qn + 4, l34 ^ 3);
            } else {
                q2A = SEL4(qn + 8, l12);
                q2C = SEL4(qn + 8, l12 ^ 3);
            }
        }
    }

    // ---- store: lanes 0-15 write slq[lane] (select from replicated regs) ----
    if (lane < 16) {
        const int t = lane >> 2, c = lane & 3;
        float r0 = SEL4(slq + 0,  c);
        float r1 = SEL4(slq + 4,  c);
        float r2 = SEL4(slq + 8,  c);
        float r3 = SEL4(slq + 12, c);
        float v  = (t & 2) ? ((t & 1) ? r3 : r2) : ((t & 1) ? r1 : r0);
        out[(size_t)item * 16 + lane] = v;
    }
}

extern "C" void kernel_launch(void* const* d_in, const int* in_sizes, int n_in,
                              void* d_out, int out_size, void* d_ws, size_t ws_size,
                              hipStream_t stream) {
    const float* log_qi = (const float*)d_in[0];
    const float* G      = (const float*)d_in[1];
    const float* rho    = (const float*)d_in[2];
    // d_in[3] = n_var — unused by the reference
    const float* alpha  = (const float*)d_in[4];
    float* out = (float*)d_out;

    const int N = in_sizes[2];              // 32768 batch items
    const int blocks = (N + 3) / 4;         // 4 items (waves) per block
    mfnet_layer_kernel<<<blocks, 256, 0, stream>>>(log_qi, G, rho, alpha, out, N);
}

// Round 4
// 85.418 us; speedup vs baseline: 2.3444x; 1.2309x over previous
//
#include <hip/hip_runtime.h>

#define LOG2E 1.4426950408889634f
#define LN2F  0.6931471805599453f
#define RS5F  0.4472135954999579f  // 1/sqrt(5)

// single-instruction ds_swizzle helpers (BitMode: src = ((dst & AND) | OR) ^ XOR)
template<int XOR, int OR, int AND>
__device__ __forceinline__ float swz(float v) {
    return __int_as_float(__builtin_amdgcn_ds_swizzle(
        __float_as_int(v), (XOR << 10) | (OR << 5) | AND));
}
#define SWZX(v, m)     swz<(m), 0, 0x1F>(v)      // butterfly xor within 32-half
#define BCAST16(v, s)  swz<0, (s), 0x10>(v)      // broadcast sublane s within 16-group

__device__ __forceinline__ float sel4(float e0, float e1, float e2, float e3, int c) {
    float lo = (c & 1) ? e1 : e0;
    float hi = (c & 1) ? e3 : e2;
    return (c & 2) ? hi : lo;
}

// 4 items per WAVE (16 lanes per item; 16 items per 256-thread block).
// Within an item's 16-lane group: u = lane&15, c1 = u>>2, c2 = u&3.
// In-lane loop j in [0,8): c0 = j>>2 in {0,1}, c3 = j&3. A-combo = (c0,c1,c2,c3);
// C-combo = its digit complement (3-c0,3-c1,3-c2,3-c3). 16 lanes x 8 j x {A,C} = 256.
// All log-quantities kept in log2 units (x LOG2E); converted by LN2F at store.
__global__ __launch_bounds__(256) void mfnet_layer_kernel(
    const float* __restrict__ log_qi,   // (N,4,4)
    const float* __restrict__ G,        // (N,8,4)
    const float* __restrict__ sqrt_2rho,// (N,)
    const float* __restrict__ alpha_ptr,// (1,)
    float* __restrict__ out,            // (N,4,4)
    int N)
{
    const int tid  = threadIdx.x;
    const int wv   = tid >> 6;
    const int lane = tid & 63;
    const int grp  = lane >> 4;
    const int u    = lane & 15;

    const int ib    = blockIdx.x * 16 + wv * 4;   // wave's first item
    const int item0 = ib + grp;
    const bool valid = item0 < N;
    const int item  = valid ? item0 : (N - 1);

    // G staged per wave: 4 items x 32 floats, padded to 36 (bank offset, 16B aligned)
    __shared__ __align__(16) float sG[4][148];
    {
        size_t gidx = (size_t)ib * 32 + (size_t)(lane * 2);
        size_t gmax = (size_t)N * 32 - 2;
        if (gidx > gmax) gidx = gmax;
        const float2 gv = *(const float2*)(G + gidx);
        const int off = (lane * 2) & 31;          // float offset within item (grp)
        *(float2*)&sG[wv][grp * 36 + off] = gv;
    }
    __syncthreads();

    const float rho   = sqrt_2rho[item];
    const float alpha = alpha_ptr[0];
    const float alm1  = 1.0f - alpha;
    const float rv    = rho * RS5F;

    const int c1 = u >> 2, c2 = u & 3;
    const float s1 = rv * (float)(2 * c1 - 3);
    const float s2 = rv * (float)(2 * c2 - 3);

    // state in log2 units, replicated across the item's 16 lanes
    float slq2[16];
    {
        const float4* lq = (const float4*)(log_qi + (size_t)item * 16);
#pragma unroll
        for (int i = 0; i < 4; ++i) {
            float4 v = lq[i];
            slq2[4*i+0] = v.x * LOG2E; slq2[4*i+1] = v.y * LOG2E;
            slq2[4*i+2] = v.z * LOG2E; slq2[4*i+3] = v.w * LOG2E;
        }
    }

    // initial softmax: rows 1,2 (A/C-selected entries), row 3 (full). Row 0 unused in round 0.
    float q1A, q1C, q2A, q2C, q3v0, q3v1, q3v2, q3v3;
    {
        float e0 = exp2f(slq2[4]), e1 = exp2f(slq2[5]), e2 = exp2f(slq2[6]), e3 = exp2f(slq2[7]);
        float inv = __builtin_amdgcn_rcpf(e0 + e1 + e2 + e3);
        q1A = sel4(e0, e1, e2, e3, c1) * inv;
        q1C = sel4(e0, e1, e2, e3, c1 ^ 3) * inv;
    }
    {
        float e0 = exp2f(slq2[8]), e1 = exp2f(slq2[9]), e2 = exp2f(slq2[10]), e3 = exp2f(slq2[11]);
        float inv = __builtin_amdgcn_rcpf(e0 + e1 + e2 + e3);
        q2A = sel4(e0, e1, e2, e3, c2) * inv;
        q2C = sel4(e0, e1, e2, e3, c2 ^ 3) * inv;
    }
    {
        float e0 = exp2f(slq2[12]), e1 = exp2f(slq2[13]), e2 = exp2f(slq2[14]), e3 = exp2f(slq2[15]);
        float inv = __builtin_amdgcn_rcpf(e0 + e1 + e2 + e3);
        q3v0 = e0 * inv; q3v1 = e1 * inv; q3v2 = e2 * inv; q3v3 = e3 * inv;
    }

    // ---- laplace-log-cdf accumulation (log2 units); pair trick: C = -A ----
    float lpA[8] = {0,0,0,0,0,0,0,0};
    float lpC[8] = {0,0,0,0,0,0,0,0};
    const float* gw = &sG[wv][grp * 36];
#pragma unroll
    for (int r = 0; r < 8; ++r) {
        float4 g = *(const float4*)(gw + r * 4);
        float b12 = fmaf(g.y, s1, g.z * s2);
        float m0  = g.x * rv;
        float m3  = g.w * rv;
        float t0  = fmaf(m0, -3.0f, b12);   // c0 = 0
        float t1  = b12 - m0;               // c0 = 1
#pragma unroll
        for (int j = 0; j < 8; ++j) {
            float tb = (j & 4) ? t1 : t0;
            float w3 = (float)(2 * (j & 3) - 3);     // -3,-1,1,3
            float x  = fmaf(m3, w3, tb);
            float tt = fabsf(x) * (-LOG2E);          // = x*log2e for x<0
            float e  = exp2f(tt);
            float lg = __log2f(fmaf(e, -0.5f, 1.0f));
            float ng = tt - 1.0f;                    // (x - ln2)*log2e for x<0
            bool neg = (x < 0.0f);
            lpA[j] += neg ? ng : lg;
            lpC[j] += neg ? lg : ng;
        }
    }

    float ex0, ex1, ex2, ex3, m;
    // U-sums over c3 with q3 weights (reused for IA/IC)
    float UA0 = lpA[0]*q3v0 + lpA[1]*q3v1 + lpA[2]*q3v2 + lpA[3]*q3v3;  // c0=0
    float UA1 = lpA[4]*q3v0 + lpA[5]*q3v1 + lpA[6]*q3v2 + lpA[7]*q3v3;  // c0=1
    float UC3 = lpC[0]*q3v3 + lpC[1]*q3v2 + lpC[2]*q3v1 + lpC[3]*q3v0;  // c0'=3
    float UC2 = lpC[4]*q3v3 + lpC[5]*q3v2 + lpC[6]*q3v1 + lpC[7]*q3v0;  // c0'=2

    // ======== round 0 (groups = c0) ========
    {
        float preQ  = q1A * q2A;
        float preQC = q1C * q2C;
        float SA0 = UA0 * preQ, SA1 = UA1 * preQ;
        float SC2 = UC2 * preQC, SC3 = UC3 * preQC;
        SA0 += SWZX(SA0,1); SA0 += SWZX(SA0,2); SA0 += SWZX(SA0,4); SA0 += SWZX(SA0,8);
        SA1 += SWZX(SA1,1); SA1 += SWZX(SA1,2); SA1 += SWZX(SA1,4); SA1 += SWZX(SA1,8);
        SC2 += SWZX(SC2,1); SC2 += SWZX(SC2,2); SC2 += SWZX(SC2,4); SC2 += SWZX(SC2,8);
        SC3 += SWZX(SC3,1); SC3 += SWZX(SC3,2); SC3 += SWZX(SC3,4); SC3 += SWZX(SC3,8);
        ex0 = SA0; ex1 = SA1; ex2 = SC2; ex3 = SC3;
    }
    slq2[0] = alm1*slq2[0] + alpha*ex0;
    slq2[1] = alm1*slq2[1] + alpha*ex1;
    slq2[2] = alm1*slq2[2] + alpha*ex2;
    slq2[3] = alm1*slq2[3] + alpha*ex3;
#pragma unroll
    for (int t = 0; t < 4; ++t) {   // round 0 renorms ALL rows
        m = fmaxf(fmaxf(slq2[4*t], slq2[4*t+1]), fmaxf(slq2[4*t+2], slq2[4*t+3]));
        slq2[4*t] -= m; slq2[4*t+1] -= m; slq2[4*t+2] -= m; slq2[4*t+3] -= m;
    }
    // refresh row 0 (full — all 4 values needed by later rounds)
    float q0v0, q0v1, q0v2, q0v3;
    {
        float e0 = exp2f(slq2[0]), e1 = exp2f(slq2[1]), e2 = exp2f(slq2[2]), e3 = exp2f(slq2[3]);
        float inv = __builtin_amdgcn_rcpf(e0 + e1 + e2 + e3);
        q0v0 = e0*inv; q0v1 = e1*inv; q0v2 = e2*inv; q0v3 = e3*inv;
    }
    // inner products over (q0,q3): valid for rounds 1-3 (q0 refreshes once, q3 never)
    float IA = q0v0 * UA0 + q0v1 * UA1;
    float IC = q0v3 * UC3 + q0v2 * UC2;
    float Pin0 = lpA[0]*q0v0 + lpA[4]*q0v1;   // round-3 A-side, group c3=c
    float Pin1 = lpA[1]*q0v0 + lpA[5]*q0v1;
    float Pin2 = lpA[2]*q0v0 + lpA[6]*q0v1;
    float Pin3 = lpA[3]*q0v0 + lpA[7]*q0v1;
    float Qin0 = lpC[3]*q0v3 + lpC[7]*q0v2;   // round-3 C-side: c3'=0 from j&3=3
    float Qin1 = lpC[2]*q0v3 + lpC[6]*q0v2;
    float Qin2 = lpC[1]*q0v3 + lpC[5]*q0v2;
    float Qin3 = lpC[0]*q0v3 + lpC[4]*q0v2;

    // ======== round 1 (groups = c1 = u>>2) ========
    {
        float SA = q2A * IA;
        float SC = q2C * IC;
        SA += SWZX(SA,1); SA += SWZX(SA,2);
        SC += SWZX(SC,1); SC += SWZX(SC,2);
        float T = SA + SWZX(SC, 12);          // C of subgroup 3-s -> s (flip bits 2,3)
        ex0 = BCAST16(T, 0); ex1 = BCAST16(T, 4); ex2 = BCAST16(T, 8); ex3 = BCAST16(T, 12);
        slq2[4] = alm1*slq2[4] + alpha*ex0;
        slq2[5] = alm1*slq2[5] + alpha*ex1;
        slq2[6] = alm1*slq2[6] + alpha*ex2;
        slq2[7] = alm1*slq2[7] + alpha*ex3;
        m = fmaxf(fmaxf(slq2[4], slq2[5]), fmaxf(slq2[6], slq2[7]));
        slq2[4] -= m; slq2[5] -= m; slq2[6] -= m; slq2[7] -= m;
        float e0 = exp2f(slq2[4]), e1 = exp2f(slq2[5]), e2 = exp2f(slq2[6]), e3 = exp2f(slq2[7]);
        float inv = __builtin_amdgcn_rcpf(e0 + e1 + e2 + e3);
        q1A = sel4(e0, e1, e2, e3, c1) * inv;
        q1C = sel4(e0, e1, e2, e3, c1 ^ 3) * inv;
    }

    // ======== round 2 (groups = c2 = u&3) ========
    {
        float SA = q1A * IA;
        float SC = q1C * IC;
        SA += SWZX(SA,4); SA += SWZX(SA,8);
        SC += SWZX(SC,4); SC += SWZX(SC,8);
        float T = SA + SWZX(SC, 3);           // flip bits 0,1
        ex0 = BCAST16(T, 0); ex1 = BCAST16(T, 1); ex2 = BCAST16(T, 2); ex3 = BCAST16(T, 3);
        slq2[8]  = alm1*slq2[8]  + alpha*ex0;
        slq2[9]  = alm1*slq2[9]  + alpha*ex1;
        slq2[10] = alm1*slq2[10] + alpha*ex2;
        slq2[11] = alm1*slq2[11] + alpha*ex3;
        m = fmaxf(fmaxf(slq2[8], slq2[9]), fmaxf(slq2[10], slq2[11]));
        slq2[8] -= m; slq2[9] -= m; slq2[10] -= m; slq2[11] -= m;
        float e0 = exp2f(slq2[8]), e1 = exp2f(slq2[9]), e2 = exp2f(slq2[10]), e3 = exp2f(slq2[11]);
        float inv = __builtin_amdgcn_rcpf(e0 + e1 + e2 + e3);
        q2A = sel4(e0, e1, e2, e3, c2) * inv;
        q2C = sel4(e0, e1, e2, e3, c2 ^ 3) * inv;
    }

    // ======== round 3 (groups = c3, in-lane) ========
    {
        float preQ  = q1A * q2A;    // post-refresh rows 1,2
        float preQC = q1C * q2C;
        float R0 = Pin0 * preQ + Qin0 * preQC;
        float R1 = Pin1 * preQ + Qin1 * preQC;
        float R2 = Pin2 * preQ + Qin2 * preQC;
        float R3 = Pin3 * preQ + Qin3 * preQC;
        R0 += SWZX(R0,1); R0 += SWZX(R0,2); R0 += SWZX(R0,4); R0 += SWZX(R0,8);
        R1 += SWZX(R1,1); R1 += SWZX(R1,2); R1 += SWZX(R1,4); R1 += SWZX(R1,8);
        R2 += SWZX(R2,1); R2 += SWZX(R2,2); R2 += SWZX(R2,4); R2 += SWZX(R2,8);
        R3 += SWZX(R3,1); R3 += SWZX(R3,2); R3 += SWZX(R3,4); R3 += SWZX(R3,8);
        slq2[12] = alm1*slq2[12] + alpha*R0;
        slq2[13] = alm1*slq2[13] + alpha*R1;
        slq2[14] = alm1*slq2[14] + alpha*R2;
        slq2[15] = alm1*slq2[15] + alpha*R3;
        m = fmaxf(fmaxf(slq2[12], slq2[13]), fmaxf(slq2[14], slq2[15]));
        slq2[12] -= m; slq2[13] -= m; slq2[14] -= m; slq2[15] -= m;
    }

    // ---- store: sublane u writes out[item*16 + u] (row=c1, col=c2) ----
    if (valid) {
        float r0 = sel4(slq2[0],  slq2[1],  slq2[2],  slq2[3],  c2);
        float r1 = sel4(slq2[4],  slq2[5],  slq2[6],  slq2[7],  c2);
        float r2 = sel4(slq2[8],  slq2[9],  slq2[10], slq2[11], c2);
        float r3 = sel4(slq2[12], slq2[13], slq2[14], slq2[15], c2);
        float vv = sel4(r0, r1, r2, r3, c1);
        out[(size_t)item * 16 + u] = vv * LN2F;
    }
}

extern "C" void kernel_launch(void* const* d_in, const int* in_sizes, int n_in,
                              void* d_out, int out_size, void* d_ws, size_t ws_size,
                              hipStream_t stream) {
    const float* log_qi = (const float*)d_in[0];
    const float* G      = (const float*)d_in[1];
    const float* rho    = (const float*)d_in[2];
    // d_in[3] = n_var — unused by the reference
    const float* alpha  = (const float*)d_in[4];
    float* out = (float*)d_out;

    const int N = in_sizes[2];                 // 32768 batch items
    const int blocks = (N + 15) / 16;          // 16 items per block (4 per wave)
    mfnet_layer_kernel<<<blocks, 256, 0, stream>>>(log_qi, G, rho, alpha, out, N);
}